// Round 1
// baseline (481.247 us; speedup 1.0000x reference)
//
#include <hip/hip_runtime.h>
#include <hip/hip_bf16.h>

#define N_EDGES_C 500000
#define D_C 128
#define C_C 50
#define K3_C 384
#define CPAD_C 64

typedef __attribute__((ext_vector_type(8))) short bf16x8;
typedef __attribute__((ext_vector_type(4))) float f32x4;

static __device__ inline short2 pack_bf16_2(float a, float b) {
    union { __hip_bfloat162 h; short2 s; } u;
    u.h = __float22bfloat162_rn(make_float2(a, b));
    return u.s;
}

// W [50][384] fp32 -> WB [64][384] bf16 (rows >= 50 zero-padded)
__global__ void wconv_kernel(const float* __restrict__ W, short* __restrict__ WB) {
    int idx = blockIdx.x * blockDim.x + threadIdx.x;
    if (idx >= CPAD_C * K3_C) return;
    int c = idx / K3_C;
    int k = idx - c * K3_C;
    float v = (c < C_C) ? W[c * K3_C + k] : 0.0f;
    union { __hip_bfloat16 b; short s; } u;
    u.b = __float2bfloat16(v);
    WB[idx] = u.s;
}

// One block = 4 waves; each wave computes 64 edges x 64 (padded) classes.
// No LDS, no barriers: A-frags direct from global (8 contiguous fp32/lane),
// B-frags from bf16 W in workspace (L1/L2 resident, reused across 4 M-tiles).
__global__ __launch_bounds__(256) void edge_mlp_kernel(
    const float* __restrict__ h, const float* __restrict__ ef,
    const int* __restrict__ src, const int* __restrict__ dst,
    const short* __restrict__ WB, const float* __restrict__ bias,
    float* __restrict__ out)
{
    const int lane = threadIdx.x & 63;
    const int wave = threadIdx.x >> 6;
    const int m = lane & 15;   // A-operand row (edge in tile); D col (class) in epilogue
    const int q = lane >> 4;   // quad
    const int kq = q * 8;      // lane's k offset inside a 32-wide K chunk

    const long wave_base = (long)blockIdx.x * 256 + (long)wave * 64;

    const float* psrc[4];
    const float* pdst[4];
    const float* pef[4];
#pragma unroll
    for (int i = 0; i < 4; ++i) {
        long ei = wave_base + i * 16 + m;
        long eic = ei < N_EDGES_C ? ei : (long)(N_EDGES_C - 1);
        int si = src[eic];
        int di = dst[eic];
        psrc[i] = h + (long)si * D_C + kq;
        pdst[i] = h + (long)di * D_C + kq;
        pef[i]  = ef + eic * D_C + kq;
    }

    // B-frag rows: lane reads WB[t*16+m][ko + kq .. +7] (W row-major == B^T layout)
    const short* wrow[4];
#pragma unroll
    for (int t = 0; t < 4; ++t)
        wrow[t] = WB + (t * 16 + m) * K3_C + kq;

    f32x4 acc[4][4];
#pragma unroll
    for (int i = 0; i < 4; ++i)
#pragma unroll
        for (int t = 0; t < 4; ++t)
            acc[i][t] = (f32x4){0.0f, 0.0f, 0.0f, 0.0f};

    auto kstep = [&](const float* const (&pr)[4], int koff, int ko) {
        bf16x8 bfr[4];
#pragma unroll
        for (int t = 0; t < 4; ++t)
            bfr[t] = *reinterpret_cast<const bf16x8*>(wrow[t] + ko);
#pragma unroll
        for (int i = 0; i < 4; ++i) {
            const float4 f0 = *reinterpret_cast<const float4*>(pr[i] + koff);
            const float4 f1 = *reinterpret_cast<const float4*>(pr[i] + koff + 4);
            short2 p0 = pack_bf16_2(f0.x, f0.y);
            short2 p1 = pack_bf16_2(f0.z, f0.w);
            short2 p2 = pack_bf16_2(f1.x, f1.y);
            short2 p3 = pack_bf16_2(f1.z, f1.w);
            bf16x8 afr = { p0.x, p0.y, p1.x, p1.y, p2.x, p2.y, p3.x, p3.y };
#pragma unroll
            for (int t = 0; t < 4; ++t)
                acc[i][t] = __builtin_amdgcn_mfma_f32_16x16x32_bf16(afr, bfr[t], acc[i][t], 0, 0, 0);
        }
    };

    // K split by feature segment: [0,128)=h[src], [128,256)=h[dst], [256,384)=e
#pragma unroll
    for (int kk = 0; kk < 128; kk += 32) kstep(psrc, kk, kk);
#pragma unroll
    for (int kk = 0; kk < 128; kk += 32) kstep(pdst, kk, 128 + kk);
#pragma unroll
    for (int kk = 0; kk < 128; kk += 32) kstep(pef, kk, 256 + kk);

    // Epilogue: D layout col = lane&15 (class), row = q*4 + r (edge in tile)
    float bv[4];
#pragma unroll
    for (int t = 0; t < 4; ++t) {
        int c = t * 16 + m;
        bv[t] = (c < C_C) ? bias[c] : 0.0f;
    }
#pragma unroll
    for (int i = 0; i < 4; ++i) {
        long er0 = wave_base + i * 16 + q * 4;
#pragma unroll
        for (int r = 0; r < 4; ++r) {
            long ei = er0 + r;
            if (ei < N_EDGES_C) {
#pragma unroll
                for (int t = 0; t < 4; ++t) {
                    int c = t * 16 + m;
                    if (c < C_C) out[ei * (long)C_C + c] = acc[i][t][r] + bv[t];
                }
            }
        }
    }
}

extern "C" void kernel_launch(void* const* d_in, const int* in_sizes, int n_in,
                              void* d_out, int out_size, void* d_ws, size_t ws_size,
                              hipStream_t stream) {
    const float* h  = (const float*)d_in[0];
    const float* ef = (const float*)d_in[1];
    const int*   src = (const int*)d_in[2];
    const int*   dst = (const int*)d_in[3];
    const float* W  = (const float*)d_in[4];
    const float* b  = (const float*)d_in[5];
    float* out = (float*)d_out;
    short* WB  = (short*)d_ws;  // 64*384*2 = 49152 B of scratch

    wconv_kernel<<<(CPAD_C * K3_C + 255) / 256, 256, 0, stream>>>(W, WB);

    const int nblocks = (N_EDGES_C + 255) / 256;  // 1954
    edge_mlp_kernel<<<nblocks, 256, 0, stream>>>(h, ef, src, dst, WB, b, out);
}

// Round 2
// 457.952 us; speedup vs baseline: 1.0509x; 1.0509x over previous
//
#include <hip/hip_runtime.h>
#include <hip/hip_bf16.h>

#define N_NODES_C 50000
#define N_EDGES_C 500000
#define D_C 128
#define C_C 50
#define K3_C 384
#define CPAD_C 64

typedef __attribute__((ext_vector_type(8))) short bf16x8;
typedef __attribute__((ext_vector_type(4))) float f32x4;

static __device__ inline short2 pack_bf16_2(float a, float b) {
    union { __hip_bfloat162 h; short2 s; } u;
    u.h = __float22bfloat162_rn(make_float2(a, b));
    return u.s;
}
static __device__ inline short tobf(float v) {
    union { __hip_bfloat16 b; short s; } u;
    u.b = __float2bfloat16(v);
    return u.s;
}

// ---------------- fast path ----------------
// ws layout: WB3 [64][128] bf16 @0 (16KB); WB2 [128][128] bf16 @16384 (32KB);
//            HW  [50000][128] f32 @49152 (25.6MB)
// WB2 row r: r<50 -> W1[r][k]=W[r][k]; 64<=r<114 -> W2[r-64][k]=W[r-64][128+k]; else 0
// WB3 row r: r<50 -> W3[r][k]=W[r][256+k]; else 0

__global__ void wprep_kernel(const float* __restrict__ W,
                             short* __restrict__ WB2, short* __restrict__ WB3) {
    int idx = blockIdx.x * blockDim.x + threadIdx.x;
    if (idx < 128 * 128) {
        int r = idx >> 7, k = idx & 127;
        float v = 0.0f;
        if (r < C_C) v = W[r * K3_C + k];
        else if (r >= 64 && r < 64 + C_C) v = W[(r - 64) * K3_C + 128 + k];
        WB2[idx] = tobf(v);
    } else if (idx < 128 * 128 + 64 * 128) {
        int j = idx - 128 * 128;
        int r = j >> 7, k = j & 127;
        float v = (r < C_C) ? W[r * K3_C + 256 + k] : 0.0f;
        WB3[j] = tobf(v);
    }
}

// HW[n][c] for c<64: sum_k h[n][k]*W1[c][k] + b[c] (0 for c>=50)
//          for c>=64: sum_k h[n][k]*W2[c-64][k]
__global__ __launch_bounds__(64) void node_gemm_kernel(
    const float* __restrict__ h, const short* __restrict__ WB2,
    const float* __restrict__ bias, float* __restrict__ HW)
{
    const int lane = threadIdx.x;
    const int m = lane & 15, q = lane >> 4, kq = q * 8;
    const long nbase = (long)blockIdx.x * 64;

    bf16x8 A[4][4];
#pragma unroll
    for (int i = 0; i < 4; ++i) {
        long ni = nbase + i * 16 + m;
        if (ni >= N_NODES_C) ni = N_NODES_C - 1;
        const float* pa = h + ni * D_C + kq;
#pragma unroll
        for (int kk = 0; kk < 4; ++kk) {
            float4 f0 = *reinterpret_cast<const float4*>(pa + kk * 32);
            float4 f1 = *reinterpret_cast<const float4*>(pa + kk * 32 + 4);
            short2 p0 = pack_bf16_2(f0.x, f0.y), p1 = pack_bf16_2(f0.z, f0.w);
            short2 p2 = pack_bf16_2(f1.x, f1.y), p3 = pack_bf16_2(f1.z, f1.w);
            A[kk][i] = (bf16x8){p0.x, p0.y, p1.x, p1.y, p2.x, p2.y, p3.x, p3.y};
        }
    }
#pragma unroll
    for (int t = 0; t < 8; ++t) {
        const short* wr = WB2 + (t * 16 + m) * D_C + kq;
        f32x4 acc[4];
#pragma unroll
        for (int i = 0; i < 4; ++i) acc[i] = (f32x4){0.f, 0.f, 0.f, 0.f};
#pragma unroll
        for (int kk = 0; kk < 4; ++kk) {
            bf16x8 bfr = *reinterpret_cast<const bf16x8*>(wr + kk * 32);
#pragma unroll
            for (int i = 0; i < 4; ++i)
                acc[i] = __builtin_amdgcn_mfma_f32_16x16x32_bf16(A[kk][i], bfr, acc[i], 0, 0, 0);
        }
        int c = t * 16 + m;
        float bv = (c < C_C) ? bias[c] : 0.0f;
#pragma unroll
        for (int i = 0; i < 4; ++i)
#pragma unroll
            for (int r = 0; r < 4; ++r) {
                long ni = nbase + i * 16 + q * 4 + r;
                if (ni < N_NODES_C) HW[ni * 128 + c] = acc[i][r] + bv;
            }
    }
}

// streaming GEMM e·W3^T + epilogue gather of HW[src](+HW[dst]+64)
__global__ __launch_bounds__(256) void edge_gemm_kernel(
    const float* __restrict__ ef, const int* __restrict__ src,
    const int* __restrict__ dst, const short* __restrict__ WB3,
    const float* __restrict__ HW, float* __restrict__ out)
{
    const int lane = threadIdx.x & 63;
    const int wave = threadIdx.x >> 6;
    const int m = lane & 15, q = lane >> 4, kq = q * 8;
    const long wave_base = (long)blockIdx.x * 256 + (long)wave * 64;

    const float* pe[4];
#pragma unroll
    for (int i = 0; i < 4; ++i) {
        long ei = wave_base + i * 16 + m;
        if (ei >= N_EDGES_C) ei = N_EDGES_C - 1;
        pe[i] = ef + ei * D_C + kq;
    }
    const short* wr[4];
#pragma unroll
    for (int t = 0; t < 4; ++t)
        wr[t] = WB3 + (t * 16 + m) * D_C + kq;

    f32x4 acc[4][4];
#pragma unroll
    for (int i = 0; i < 4; ++i)
#pragma unroll
        for (int t = 0; t < 4; ++t)
            acc[i][t] = (f32x4){0.f, 0.f, 0.f, 0.f};

#pragma unroll
    for (int kk = 0; kk < 4; ++kk) {
        bf16x8 bfr[4];
#pragma unroll
        for (int t = 0; t < 4; ++t)
            bfr[t] = *reinterpret_cast<const bf16x8*>(wr[t] + kk * 32);
#pragma unroll
        for (int i = 0; i < 4; ++i) {
            float4 f0 = *reinterpret_cast<const float4*>(pe[i] + kk * 32);
            float4 f1 = *reinterpret_cast<const float4*>(pe[i] + kk * 32 + 4);
            short2 p0 = pack_bf16_2(f0.x, f0.y), p1 = pack_bf16_2(f0.z, f0.w);
            short2 p2 = pack_bf16_2(f1.x, f1.y), p3 = pack_bf16_2(f1.z, f1.w);
            bf16x8 afr = {p0.x, p0.y, p1.x, p1.y, p2.x, p2.y, p3.x, p3.y};
#pragma unroll
            for (int t = 0; t < 4; ++t)
                acc[i][t] = __builtin_amdgcn_mfma_f32_16x16x32_bf16(afr, bfr[t], acc[i][t], 0, 0, 0);
        }
    }

    // epilogue: D col = class (t*16+m), row = edge (q*4+r) within tile i
#pragma unroll
    for (int i = 0; i < 4; ++i) {
#pragma unroll
        for (int r = 0; r < 4; ++r) {
            long ei = wave_base + i * 16 + q * 4 + r;
            if (ei < N_EDGES_C) {
                int si = src[ei];
                int di = dst[ei];
                const float* g1 = HW + (long)si * 128;       // W1 part + bias
                const float* g2 = HW + (long)di * 128 + 64;  // W2 part
#pragma unroll
                for (int t = 0; t < 4; ++t) {
                    int c = t * 16 + m;
                    if (c < C_C)
                        out[ei * (long)C_C + c] = acc[i][t][r] + g1[c] + g2[c];
                }
            }
        }
    }
}

// ---------------- fallback path (round-1 kernel, needs only 49KB ws) ----------------
__global__ void wconv_kernel(const float* __restrict__ W, short* __restrict__ WB) {
    int idx = blockIdx.x * blockDim.x + threadIdx.x;
    if (idx >= CPAD_C * K3_C) return;
    int c = idx / K3_C;
    int k = idx - c * K3_C;
    float v = (c < C_C) ? W[c * K3_C + k] : 0.0f;
    WB[idx] = tobf(v);
}

__global__ __launch_bounds__(256) void edge_mlp_kernel(
    const float* __restrict__ h, const float* __restrict__ ef,
    const int* __restrict__ src, const int* __restrict__ dst,
    const short* __restrict__ WB, const float* __restrict__ bias,
    float* __restrict__ out)
{
    const int lane = threadIdx.x & 63;
    const int wave = threadIdx.x >> 6;
    const int m = lane & 15;
    const int q = lane >> 4;
    const int kq = q * 8;
    const long wave_base = (long)blockIdx.x * 256 + (long)wave * 64;

    const float* psrc[4];
    const float* pdst[4];
    const float* pef[4];
#pragma unroll
    for (int i = 0; i < 4; ++i) {
        long ei = wave_base + i * 16 + m;
        long eic = ei < N_EDGES_C ? ei : (long)(N_EDGES_C - 1);
        int si = src[eic];
        int di = dst[eic];
        psrc[i] = h + (long)si * D_C + kq;
        pdst[i] = h + (long)di * D_C + kq;
        pef[i]  = ef + eic * D_C + kq;
    }
    const short* wrow[4];
#pragma unroll
    for (int t = 0; t < 4; ++t)
        wrow[t] = WB + (t * 16 + m) * K3_C + kq;

    f32x4 acc[4][4];
#pragma unroll
    for (int i = 0; i < 4; ++i)
#pragma unroll
        for (int t = 0; t < 4; ++t)
            acc[i][t] = (f32x4){0.0f, 0.0f, 0.0f, 0.0f};

    auto kstep = [&](const float* const (&pr)[4], int koff, int ko) {
        bf16x8 bfr[4];
#pragma unroll
        for (int t = 0; t < 4; ++t)
            bfr[t] = *reinterpret_cast<const bf16x8*>(wrow[t] + ko);
#pragma unroll
        for (int i = 0; i < 4; ++i) {
            const float4 f0 = *reinterpret_cast<const float4*>(pr[i] + koff);
            const float4 f1 = *reinterpret_cast<const float4*>(pr[i] + koff + 4);
            short2 p0 = pack_bf16_2(f0.x, f0.y);
            short2 p1 = pack_bf16_2(f0.z, f0.w);
            short2 p2 = pack_bf16_2(f1.x, f1.y);
            short2 p3 = pack_bf16_2(f1.z, f1.w);
            bf16x8 afr = { p0.x, p0.y, p1.x, p1.y, p2.x, p2.y, p3.x, p3.y };
#pragma unroll
            for (int t = 0; t < 4; ++t)
                acc[i][t] = __builtin_amdgcn_mfma_f32_16x16x32_bf16(afr, bfr[t], acc[i][t], 0, 0, 0);
        }
    };
#pragma unroll
    for (int kk = 0; kk < 128; kk += 32) kstep(psrc, kk, kk);
#pragma unroll
    for (int kk = 0; kk < 128; kk += 32) kstep(pdst, kk, 128 + kk);
#pragma unroll
    for (int kk = 0; kk < 128; kk += 32) kstep(pef, kk, 256 + kk);

    float bv[4];
#pragma unroll
    for (int t = 0; t < 4; ++t) {
        int c = t * 16 + m;
        bv[t] = (c < C_C) ? bias[c] : 0.0f;
    }
#pragma unroll
    for (int i = 0; i < 4; ++i) {
        long er0 = wave_base + i * 16 + q * 4;
#pragma unroll
        for (int r = 0; r < 4; ++r) {
            long ei = er0 + r;
            if (ei < N_EDGES_C) {
#pragma unroll
                for (int t = 0; t < 4; ++t) {
                    int c = t * 16 + m;
                    if (c < C_C) out[ei * (long)C_C + c] = acc[i][t][r] + bv[t];
                }
            }
        }
    }
}

extern "C" void kernel_launch(void* const* d_in, const int* in_sizes, int n_in,
                              void* d_out, int out_size, void* d_ws, size_t ws_size,
                              hipStream_t stream) {
    const float* h   = (const float*)d_in[0];
    const float* ef  = (const float*)d_in[1];
    const int*   src = (const int*)d_in[2];
    const int*   dst = (const int*)d_in[3];
    const float* W   = (const float*)d_in[4];
    const float* b   = (const float*)d_in[5];
    float* out = (float*)d_out;

    const size_t REQ = 49152 + (size_t)N_NODES_C * 128 * 4;  // ~25.65 MB
    if (ws_size >= REQ) {
        short* WB3 = (short*)d_ws;                        // 16 KB
        short* WB2 = (short*)((char*)d_ws + 16384);       // 32 KB
        float* HW  = (float*)((char*)d_ws + 49152);       // 25.6 MB

        wprep_kernel<<<(128 * 128 + 64 * 128 + 255) / 256, 256, 0, stream>>>(W, WB2, WB3);
        node_gemm_kernel<<<(N_NODES_C + 63) / 64, 64, 0, stream>>>(h, WB2, b, HW);
        edge_gemm_kernel<<<(N_EDGES_C + 255) / 256, 256, 0, stream>>>(ef, src, dst, WB3, HW, out);
    } else {
        short* WB = (short*)d_ws;  // 49152 B
        wconv_kernel<<<(CPAD_C * K3_C + 255) / 256, 256, 0, stream>>>(W, WB);
        edge_mlp_kernel<<<(N_EDGES_C + 255) / 256, 256, 0, stream>>>(h, ef, src, dst, WB, b, out);
    }
}